// Round 15
// baseline (257.154 us; speedup 1.0000x reference)
//
#include <hip/hip_runtime.h>
#include <hip/hip_bf16.h>
#include <stdint.h>
#include <math.h>

typedef __attribute__((ext_vector_type(8))) short bf16x8;
typedef __attribute__((ext_vector_type(8))) unsigned short ushort8v;
typedef __attribute__((ext_vector_type(4))) float f32x4;
typedef __attribute__((ext_vector_type(2))) float f32x2;
typedef __attribute__((ext_vector_type(4))) unsigned int u32x4;
typedef unsigned long long ull;

__device__ __forceinline__ void load_lds16(const void* g, void* l){
  __builtin_amdgcn_global_load_lds((const __attribute__((address_space(1))) void*)g,
                                   (__attribute__((address_space(3))) void*)l, 16, 0, 0);
}

__device__ __forceinline__ float bf2f(unsigned int u){
  union { unsigned int i; float f; } x; x.i = u << 16; return x.f;
}
__device__ __forceinline__ unsigned short f2bf(float f){
  __hip_bfloat16 h = __float2bfloat16(f);
  unsigned short u;
  __builtin_memcpy(&u, &h, 2);
  return u;
}

// ---------- fused weight transposes + bucket-cursor init (one dispatch) ----------
__global__ void wtrans4_kernel(const float* __restrict__ W1, unsigned short* __restrict__ Wt1,
                               const float* __restrict__ Wc1, unsigned short* __restrict__ Wtc1,
                               const float* __restrict__ Wc2, unsigned short* __restrict__ Wtc2,
                               const float* __restrict__ Wf, unsigned short* __restrict__ Wtf,
                               int NB, int cap1r, int cap2r, int* __restrict__ bcur,
                               unsigned* __restrict__ Tz0, unsigned* __restrict__ Tz1){
  int idx = blockIdx.x*256 + threadIdx.x;
  if (idx >= 245760){                       // binit tail
    int i = idx - 245760;
    if (i < NB) bcur[i] = i*cap1r;
    else if (i < 2*NB) bcur[i] = NB*cap1r + (i - NB)*cap2r;
    else if (i < 2*NB + 32) Tz0[i - 2*NB] = 0u;
    else if (i < 2*NB + 64) Tz1[i - 2*NB - 32] = 0u;
    return;
  }
  const float* W; unsigned short* Wt; int K, N;
  if (idx < 131072){ W = W1; Wt = Wt1; K = 512; N = 256; }
  else if (idx < 163840){ idx -= 131072; W = Wc1; Wt = Wtc1; K = 256; N = 128; }
  else if (idx < 196608){ idx -= 163840; W = Wc2; Wt = Wtc2; K = 256; N = 128; }
  else { idx -= 196608; W = Wf; Wt = Wtf; K = 768; N = 40; }
  int nn = idx / K, kk = idx - nn*K;
  float v = (nn < N) ? W[(size_t)kk*N + nn] : 0.f;
  Wt[idx] = f2bf(v);
}

// ---------- graph preprocessing (bucketed, atomic-light, fixed-capacity) ----------
// Buckets of 128 destination nodes. Staging AND the final CSR are both
// bucket-strided with fixed +17sigma capacities -> NO global scans needed.
// partA partitions edges into staging; degpartB (one kernel) counts,
// LDS-scans padded degrees, writes dis + per-bucket goff[129], scatters
// into csr with LDS cursors, pads nodes to 8-multiples, fills 64 slack
// records. PCH=2048 -> ~6 blocks/CU (halves partA's drain tail vs 4096).
#define PCH 2048

// Pass A: partition PCH-edge chunks into bucket staging
__global__ __launch_bounds__(256) void partA_kernel(
    const int* __restrict__ ei1, int E1, const int* __restrict__ ei2, int E2,
    int* __restrict__ bcur, unsigned* __restrict__ staging, int NB)
{
  const int set = blockIdx.y;
  const int* __restrict__ ei = set ? ei2 : ei1;
  const int E = set ? E2 : E1;
  int* __restrict__ cur = bcur + set*NB;
  __shared__ int hist[400];
  __shared__ int resv[400];
  const int tid = threadIdx.x;
  const int base = blockIdx.x * PCH;
  if (base >= E) return;
  for (int b = tid; b < NB; b += 256) hist[b] = 0;
  __syncthreads();

  if (base + PCH <= E){
    // fast path: 8 edges/thread, rows+cols vector-loaded up front (4x int4 in flight)
    const int t0 = base + tid*8;
    int4 c[2], r[2];
    #pragma unroll
    for (int j = 0; j < 2; ++j) c[j] = *(const int4*)(ei + E + t0 + j*4);
    #pragma unroll
    for (int j = 0; j < 2; ++j) r[j] = *(const int4*)(ei + t0 + j*4);
    #pragma unroll
    for (int j = 0; j < 2; ++j){
      atomicAdd(&hist[c[j].x >> 7], 1); atomicAdd(&hist[c[j].y >> 7], 1);
      atomicAdd(&hist[c[j].z >> 7], 1); atomicAdd(&hist[c[j].w >> 7], 1);
    }
    __syncthreads();
    for (int b = tid; b < NB; b += 256){
      int hc = hist[b];
      resv[b] = hc ? atomicAdd(&cur[b], hc) : 0;
      hist[b] = 0;                      // reuse as local cursor
    }
    __syncthreads();
    #pragma unroll
    for (int j = 0; j < 2; ++j){
      int cc, rr, b, s;
      cc = c[j].x; rr = r[j].x; b = cc >> 7;
      s = resv[b] + atomicAdd(&hist[b], 1);
      staging[s] = ((unsigned)rr << 7) | (unsigned)(cc & 127);
      cc = c[j].y; rr = r[j].y; b = cc >> 7;
      s = resv[b] + atomicAdd(&hist[b], 1);
      staging[s] = ((unsigned)rr << 7) | (unsigned)(cc & 127);
      cc = c[j].z; rr = r[j].z; b = cc >> 7;
      s = resv[b] + atomicAdd(&hist[b], 1);
      staging[s] = ((unsigned)rr << 7) | (unsigned)(cc & 127);
      cc = c[j].w; rr = r[j].w; b = cc >> 7;
      s = resv[b] + atomicAdd(&hist[b], 1);
      staging[s] = ((unsigned)rr << 7) | (unsigned)(cc & 127);
    }
  } else {
    // tail path: guarded scalar
    for (int i = 0; i < PCH/256; ++i){
      int e = base + i*256 + tid;
      if (e < E) atomicAdd(&hist[ei[E + e] >> 7], 1);
    }
    __syncthreads();
    for (int b = tid; b < NB; b += 256){
      int hc = hist[b];
      resv[b] = hc ? atomicAdd(&cur[b], hc) : 0;
      hist[b] = 0;
    }
    __syncthreads();
    for (int i = 0; i < PCH/256; ++i){
      int e = base + i*256 + tid;
      if (e < E){
        int c = ei[E + e], r = ei[e];
        int b = c >> 7;
        int s = resv[b] + atomicAdd(&hist[b], 1);
        staging[s] = ((unsigned)r << 7) | (unsigned)(c & 127);
      }
    }
  }
}

// Fused: count + LDS scan + dis/goff write + local scatter + pad + slack fill.
// goff layout: [b*129 + local] = absolute record offset of node start;
// slot 128 = bucket end-of-used. csr is bucket-strided (capb records/bucket).
__global__ __launch_bounds__(256) void degpartB_kernel(
    const unsigned* __restrict__ staging, const int* __restrict__ bcur,
    float* __restrict__ dis1, float* __restrict__ dis2,
    int* __restrict__ goff1, int* __restrict__ goff2,
    unsigned* __restrict__ csr1, unsigned* __restrict__ csr2,
    int NB, int n, unsigned padrow, int cap1r, int cap2r, int capb1, int capb2)
{
  const int set = blockIdx.y;
  float* __restrict__ dis = set ? dis2 : dis1;
  int* __restrict__ goff = set ? goff2 : goff1;
  unsigned* __restrict__ csr = set ? csr2 : csr1;
  const int capb = set ? capb2 : capb1;
  const int b = blockIdx.x;
  const int nodebase = b << 7;
  const int nn = min(128, n - nodebase);
  if (nn <= 0) return;
  __shared__ int cnt[128];
  __shared__ int offv[129];
  __shared__ int curl[128];
  const int tid = threadIdx.x;
  if (tid < 128) cnt[tid] = 0;
  __syncthreads();
  const int s0 = set ? (NB*cap1r + b*cap2r) : (b*cap1r);
  const int s1 = bcur[set*NB + b];
  for (int i = s0 + tid; i < s1; i += 256)
    atomicAdd(&cnt[staging[i] & 127], 1);
  __syncthreads();
  // Hillis-Steele inclusive scan of padded counts (128 entries, in curl)
  int pc = 0;
  if (tid < 128){ pc = (cnt[tid] + 7) & ~7; curl[tid] = pc; }
  __syncthreads();
  for (int o = 1; o < 128; o <<= 1){
    int t = 0;
    if (tid < 128 && tid >= o) t = curl[tid - o];
    __syncthreads();
    if (tid < 128) curl[tid] += t;
    __syncthreads();
  }
  const int cbase = b * capb;
  if (tid < 128){
    offv[tid] = cbase + curl[tid] - pc;       // exclusive start
    if (tid == 127) offv[128] = cbase + curl[127];
  }
  __syncthreads();
  if (tid <= 128) goff[b*129 + tid] = offv[tid];
  if (tid < nn){
    int c = cnt[tid];
    dis[nodebase + tid] = (c > 0) ? (1.0f/sqrtf((float)c)) : 0.f;
  }
  if (tid < 128) curl[tid] = 0;
  __syncthreads();
  // local scatter with LDS cursors (no global atomics)
  for (int i = s0 + tid; i < s1; i += 256){
    unsigned v = staging[i];
    int cl = v & 127;
    int p = offv[cl] + atomicAdd(&curl[cl], 1);
    csr[p] = v >> 7;
  }
  __syncthreads();
  // pad each node to its 8-multiple region; fill 64 slack records past end
  for (int c = tid; c < 128; c += 256){
    int p1 = offv[c + 1];
    for (int p = offv[c] + cnt[c]; p < p1; ++p) csr[p] = padrow;
  }
  if (tid < 64) csr[offv[128] + tid] = padrow;
}

// ---------- GCN aggregation: out[c] = dis[c] * sum_e T_set[r] + b ----------
// T rows PRE-SCALED by dis_set[r], fp8 e4m3 (128B/row = 2 lines/edge).
// KN=16 consecutive nodes per wave -> 6250 waves total (~24/CU): SINGLE
// occupancy round, no drain tail (R12's KN=8 ran 1.5 rounds -> 70% occ).
// One 2-stage pipeline streams the contiguous padded-CSR range; node
// boundaries via shfl-indexed register cache (wave-uniform). KN | 128 so
// a wave never crosses a bucket.
#define KN 16
__global__ __launch_bounds__(256) void conv_kernel(
    const int* __restrict__ goff1, const unsigned* __restrict__ csr1, const float* __restrict__ dis1,
    const int* __restrict__ goff2, const unsigned* __restrict__ csr2, const float* __restrict__ dis2,
    const unsigned char* __restrict__ Tbase,   // [2][ntab][128] fp8
    const float* __restrict__ bias, unsigned short* __restrict__ outR,
    int n, int ntab)
{
  const int set = blockIdx.y;
  const int* __restrict__ goff = set ? goff2 : goff1;
  const float* __restrict__ dis = set ? dis2 : dis1;
  const unsigned* __restrict__ csrq = set ? csr2 : csr1;
  const int col_ofs = set ? 128 : 0;
  const unsigned* __restrict__ tab =
      (const unsigned*)(Tbase + (size_t)set * ntab * 128);

  const int wv0 = (blockIdx.x*4 + (threadIdx.x >> 6)) * KN;
  if (wv0 >= n) return;
  const int wend = min(n, wv0 + KN);
  const int l = threadIdx.x & 63;
  const int half = l >> 5, lf = l & 31;
  const float b0 = bias[lf*4 + 0], b1 = bias[lf*4 + 1];
  const float b2 = bias[lf*4 + 2], b3 = bias[lf*4 + 3];

  // lanes 0..KN hold goff[node .. bucket-local]; shfl-indexed boundary cache
  const int gbase = (wv0 >> 7)*129 + (wv0 & 127);
  const int offs = goff[gbase + min(l, wend - wv0)];
  const int cstart = __shfl(offs, 0, 64);
  const int pend   = __shfl(offs, wend - wv0, 64);
  int node = wv0;
  int nxt  = __shfl(offs, min(1, wend - wv0), 64);

  float ax = 0.f, ay = 0.f, az = 0.f, aw = 0.f;

#define EMIT_NODE { \
    float rx = ax + __shfl_xor(ax, 32, 64); \
    float ry = ay + __shfl_xor(ay, 32, 64); \
    float rz = az + __shfl_xor(az, 32, 64); \
    float rw = aw + __shfl_xor(aw, 32, 64); \
    if (half == 0){ \
      const float dc = dis[node]; \
      ull ov = (ull)((unsigned)f2bf(fmaf(dc, rx, b0)) | ((unsigned)f2bf(fmaf(dc, ry, b1)) << 16)) \
             | ((ull)((unsigned)f2bf(fmaf(dc, rz, b2)) | ((unsigned)f2bf(fmaf(dc, rw, b3)) << 16)) << 32); \
      __builtin_nontemporal_store(ov, (ull*)&outR[(size_t)node*256 + col_ofs + lf*4]); \
    } \
    ax = ay = az = aw = 0.f; }
#define DRAIN(CUR) \
    while (node < wend && (CUR) == nxt){ \
      EMIT_NODE \
      ++node; \
      nxt = __shfl(offs, min(node + 1 - wv0, KN), 64); \
    }

  DRAIN(cstart)                              // leading empty nodes

  const int nbat = (pend - cstart) >> 3;     // 8-edge batches, exact (padded)
  if (nbat > 0){
    const unsigned* cp = csrq + cstart + half*4;
    u32x4 qa, qb;
    unsigned va0, va1, va2, va3, vb0, vb1, vb2, vb3;

#define LQ(q, B) q = __builtin_nontemporal_load((const u32x4*)(cp + (B)*8));
#define GATH(v, q) \
    v##0 = tab[(size_t)q.x * 32 + lf]; \
    v##1 = tab[(size_t)q.y * 32 + lf]; \
    v##2 = tab[(size_t)q.z * 32 + lf]; \
    v##3 = tab[(size_t)q.w * 32 + lf];
#define FMA1(v) { \
    f32x2 lo = __builtin_amdgcn_cvt_pk_f32_fp8((int)v, false); \
    f32x2 hi = __builtin_amdgcn_cvt_pk_f32_fp8((int)v, true);  \
    ax += lo.x; ay += lo.y; az += hi.x; aw += hi.y; }
#define FMAB(v) { FMA1(v##0) FMA1(v##1) FMA1(v##2) FMA1(v##3) }

    LQ(qa, 0)
    GATH(va, qa)
    LQ(qb, 1)
    int b = 0;
    while (b + 2 <= nbat){
      LQ(qa, b + 2)              // speculative reads stay inside filled bucket (64-slack)
      GATH(vb, qb)
      FMAB(va)
      DRAIN(cstart + (b + 1)*8)
      LQ(qb, b + 3)
      GATH(va, qa)               // pad/slack rows hit the zeroed T row; harmless
      FMAB(vb)
      DRAIN(cstart + (b + 2)*8)
      b += 2;
    }
    if (b < nbat){
      FMAB(va)
      DRAIN(cstart + nbat*8)
    }
#undef LQ
#undef GATH
#undef FMA1
#undef FMAB
  }
  while (node < wend){ EMIT_NODE ++node; }
#undef EMIT_NODE
#undef DRAIN
}

// ---------- bf16 MFMA GEMM, m97-style 2-barrier loop ----------
// Thread count = WGM*WGN*64 (256 for most instances; 512 for BN=256 GEMM1).
// A [M x K] bf16 row-major (lda); AF32: A is f32, converted to bf16 during
// reg-staging (fuses the cvt pass; BN=256 single-pass reads x ONCE).
// Bt = B^T stored [BN_total x K] bf16.
// EPI 1: +bias, relu, bf16 store;
// EPI 2: A = 3 slabs (h|R1|R2, lda=256 each), +bias, fused log_softmax, f32 store;
// EPI 4: dual fp8 table store T[set][row][col] = fp8(vv * dis_set[row]).
template<int FM, int FN, int WGM, int WGN, int EPI, bool AF32>
__global__ __launch_bounds__(WGM*WGN*64, (WGM*WGN*64) == 512 ? 4 : 2) void gemm_kernel(
    const unsigned short* __restrict__ A0, const float* __restrict__ Af,
    const unsigned short* __restrict__ A1, const unsigned short* __restrict__ A2,
    const unsigned short* __restrict__ Bt, const float* __restrict__ bias,
    void* __restrict__ Cout, int M, int K, int lda, int ldc,
    const float* __restrict__ d1, const float* __restrict__ d2, int ntab)
{
  constexpr int THREADS = WGM*WGN*64;
  constexpr int BM = WGM*FM*16;
  constexpr int BN = WGN*FN*16;
  constexpr int BK = 32;
  constexpr int AJ = (BM*BK/8)/THREADS;   // 16B chunks per thread for A
  constexpr int BJ = (BN*BK/8)/THREADS;   // 16B chunks per thread for B
  static_assert(BM == 128, "staging assumes BM==128");
  __shared__ unsigned short As[BM][BK];
  __shared__ unsigned short Bs[BN][BK];
  const int tid = threadIdx.x;
  const int w = tid >> 6, l = tid & 63;
  const int wr = w / WGN, wc = w % WGN;
  const int m0 = blockIdx.x*BM, n0 = blockIdx.y*BN;
  f32x4 acc[FM][FN] = {};
  const int nsteps = K / BK;
  for (int s = 0; s < nsteps; ++s){
    const int k0 = s*BK;
    const unsigned short* Asrc = A0;
    int kin = k0;
    if constexpr (EPI == 2){
      int slab = k0 >> 8;
      Asrc = (slab == 0) ? A0 : ((slab == 1) ? A1 : A2);
      kin = k0 & 255;
    }
    __syncthreads();
    if constexpr (AF32){
      #pragma unroll
      for (int j = 0; j < AJ; ++j){        // A: load f32, cvt, store 16B to LDS
        int idx = j*THREADS + tid;
        int row = idx >> 2, kq = idx & 3;
        int rg = m0 + row; rg = (rg < M) ? rg : (M - 1);
        const float* src = Af + (size_t)rg*lda + kin + kq*8;
        float4 a = *(const float4*)src;
        float4 b2 = *(const float4*)(src + 4);
        ushort8v u;
        u[0] = f2bf(a.x);  u[1] = f2bf(a.y);  u[2] = f2bf(a.z);  u[3] = f2bf(a.w);
        u[4] = f2bf(b2.x); u[5] = f2bf(b2.y); u[6] = f2bf(b2.z); u[7] = f2bf(b2.w);
        *(ushort8v*)((char*)&As[0][0] + (size_t)idx*16) = u;
      }
    } else {
      #pragma unroll
      for (int j = 0; j < AJ; ++j){        // A: async 16B global->LDS
        int idx = j*THREADS + tid;
        int row = idx >> 2, kq = idx & 3;
        int rg = m0 + row; rg = (rg < M) ? rg : (M - 1);
        load_lds16(Asrc + (size_t)rg*lda + kin + kq*8,
                   ((char*)&As[0][0]) + (size_t)(j*THREADS + w*64)*16);
      }
    }
    #pragma unroll
    for (int j = 0; j < BJ; ++j){          // Bt: [n][k] layout, same pattern as A
      int idx = j*THREADS + tid;
      int row = idx >> 2, kq = idx & 3;
      load_lds16(Bt + (size_t)(n0 + row)*K + k0 + kq*8,
                 ((char*)&Bs[0][0]) + (size_t)(j*THREADS + w*64)*16);
    }
    __syncthreads();
    bf16x8 af[FM], bfr[FN];
    const int kofs = (l >> 4)*8, l16 = l & 15;
    #pragma unroll
    for (int mi = 0; mi < FM; ++mi)
      af[mi] = *(const bf16x8*)&As[wr*FM*16 + mi*16 + l16][kofs];
    #pragma unroll
    for (int ni = 0; ni < FN; ++ni)
      bfr[ni] = *(const bf16x8*)&Bs[wc*FN*16 + ni*16 + l16][kofs];
    #pragma unroll
    for (int mi = 0; mi < FM; ++mi)
      #pragma unroll
      for (int ni = 0; ni < FN; ++ni)
        acc[mi][ni] = __builtin_amdgcn_mfma_f32_16x16x32_bf16(af[mi], bfr[ni], acc[mi][ni], 0, 0, 0);
  }
  const int lg = l >> 4, lc = l & 15;
  if constexpr (EPI == 2){
    float* O = (float*)Cout;
    #pragma unroll
    for (int mi = 0; mi < FM; ++mi){
      #pragma unroll
      for (int i = 0; i < 4; ++i){
        int row = m0 + wr*FM*16 + mi*16 + lg*4 + i;
        float v[FN];
        float mx = -1e30f;
        #pragma unroll
        for (int ni = 0; ni < FN; ++ni){
          int col = ni*16 + lc;                       // WGN==1, n0==0
          v[ni] = acc[mi][ni][i] + ((col < 40) ? bias[col] : 0.f);
          if (col < 40) mx = fmaxf(mx, v[ni]);
        }
        #pragma unroll
        for (int d = 1; d < 16; d <<= 1) mx = fmaxf(mx, __shfl_xor(mx, d, 64));
        float se = 0.f;
        #pragma unroll
        for (int ni = 0; ni < FN; ++ni){
          int col = ni*16 + lc;
          if (col < 40) se += expf(v[ni] - mx);
        }
        #pragma unroll
        for (int d = 1; d < 16; d <<= 1) se += __shfl_xor(se, d, 64);
        float lse = logf(se);
        if (row < M){
          #pragma unroll
          for (int ni = 0; ni < FN; ++ni){
            int col = ni*16 + lc;
            if (col < 40) O[(size_t)row*40 + col] = v[ni] - mx - lse;
          }
        }
      }
    }
  } else if constexpr (EPI == 4){
    unsigned char* T = (unsigned char*)Cout;            // [2][ntab][128]
    #pragma unroll
    for (int mi = 0; mi < FM; ++mi){
      #pragma unroll
      for (int i = 0; i < 4; ++i){
        int row = m0 + wr*FM*16 + mi*16 + lg*4 + i;
        if (row >= M) continue;
        float s1 = d1[row], s2 = d2[row];
        #pragma unroll
        for (int ni = 0; ni < FN; ++ni){
          int col = n0 + wc*FN*16 + ni*16 + lc;        // [0,128)
          float vv = acc[mi][ni][i];
          unsigned p1 = (unsigned)__builtin_amdgcn_cvt_pk_fp8_f32(vv*s1, vv*s1, 0, false);
          unsigned p2 = (unsigned)__builtin_amdgcn_cvt_pk_fp8_f32(vv*s2, vv*s2, 0, false);
          T[(size_t)row*128 + col] = (unsigned char)(p1 & 0xff);
          T[((size_t)ntab + row)*128 + col] = (unsigned char)(p2 & 0xff);
        }
      }
    }
  } else {
    unsigned short* C = (unsigned short*)Cout;
    #pragma unroll
    for (int mi = 0; mi < FM; ++mi){
      #pragma unroll
      for (int i = 0; i < 4; ++i){
        int row = m0 + wr*FM*16 + mi*16 + lg*4 + i;
        if (row >= M) continue;
        #pragma unroll
        for (int ni = 0; ni < FN; ++ni){
          int col = n0 + wc*FN*16 + ni*16 + lc;
          float vv = acc[mi][ni][i];
          if constexpr (EPI == 1){ vv += bias[col]; vv = fmaxf(vv, 0.f); }
          C[(size_t)row*ldc + col] = f2bf(vv);
        }
      }
    }
  }
}

extern "C" void kernel_launch(void* const* d_in, const int* in_sizes, int n_in,
                              void* d_out, int out_size, void* d_ws, size_t ws_size,
                              hipStream_t stream)
{
  (void)n_in; (void)out_size;
  const float* x      = (const float*)d_in[0];
  const int*   ei1    = (const int*)d_in[1];
  const int*   ei2    = (const int*)d_in[2];
  const float* W_lin1 = (const float*)d_in[3];
  const float* b_lin1 = (const float*)d_in[4];
  const float* W_c1   = (const float*)d_in[5];
  const float* b_c1   = (const float*)d_in[6];
  const float* W_c2   = (const float*)d_in[7];
  const float* b_c2   = (const float*)d_in[8];
  const float* W_lin2 = (const float*)d_in[9];
  const float* b_lin2 = (const float*)d_in[10];

  const int N  = in_sizes[0] / 512;
  const int E1 = in_sizes[1] / 2;
  const int E2 = in_sizes[2] / 2;
  const int ntab = N + 1;                    // +1 zero row for pad edges
  const int NB = (N + 127) >> 7;             // destination buckets of 128 nodes
  // fixed per-bucket staging capacities (uniform edges: mean + >17 sigma)
  const int cap1r = (((E1 + NB - 1)/NB + 768) + 63) & ~63;
  const int cap2r = (((E2 + NB - 1)/NB + 1536) + 63) & ~63;
  // fixed per-bucket CSR capacities: mean + 17 sigma + max pad (7*128) + 64 slack
  const int mb1 = (int)(128.0*E1/N), mb2 = (int)(128.0*E2/N);
  const int capb1 = (mb1 + (int)(17.0*sqrt((double)mb1)) + 896 + 64 + 63) & ~63;
  const int capb2 = (mb2 + (int)(17.0*sqrt((double)mb2)) + 896 + 64 + 63) & ~63;

  char* base = (char*)d_ws;
  size_t off = 0;
  auto alloc = [&](size_t bytes) -> char* {
    off = (off + 255) & ~(size_t)255;
    char* r = base + off;
    off += bytes;
    return r;
  };

  unsigned short* h    = (unsigned short*)alloc((size_t)N*256*2);
  unsigned char*  T    = (unsigned char*)alloc((size_t)2*ntab*128); // fp8 scaled tables
  unsigned short* R1   = (unsigned short*)alloc((size_t)N*256*2);
  unsigned short* R2   = (unsigned short*)alloc((size_t)N*256*2);
  unsigned short* Wt1  = (unsigned short*)alloc((size_t)256*512*2);
  unsigned short* Wtc1 = (unsigned short*)alloc((size_t)128*256*2);
  unsigned short* Wtc2 = (unsigned short*)alloc((size_t)128*256*2);
  unsigned short* Wtf  = (unsigned short*)alloc((size_t)64*768*2); // W_lin2^T padded to 64 cols
  float* dis1 = (float*)alloc((size_t)N*4);
  float* dis2 = (float*)alloc((size_t)N*4);
  int* goff1 = (int*)alloc((size_t)NB*129*4);
  int* goff2 = (int*)alloc((size_t)NB*129*4);
  int* bcur  = (int*)alloc((size_t)2*NB*4);
  unsigned* csr1 = (unsigned*)alloc((size_t)NB*capb1*4);
  unsigned* csr2 = (unsigned*)alloc((size_t)NB*capb2*4);
  unsigned* staging = (unsigned*)alloc((size_t)NB*((size_t)cap1r + cap2r)*4);
  if (off > ws_size) return;   // workspace insufficient -> visible validation failure

  int mt = (N + 127)/128;
  int nwv = (N + KN - 1)/KN;
  int cb = (nwv + 3)/4;

  // --- fused weight transposes + bucket-cursor init ---
  wtrans4_kernel<<<(245760 + 2*NB + 64 + 255)/256, 256, 0, stream>>>(
      W_lin1, Wt1, W_c1, Wtc1, W_c2, Wtc2, W_lin2, Wtf,
      NB, cap1r, cap2r, bcur,
      (unsigned*)(T + (size_t)N*128), (unsigned*)(T + ((size_t)ntab + N)*128));
  // h = relu(x @ W_lin1 + b): BN=256 single pass, x f32 read ONCE (fused cvt)
  gemm_kernel<4,4,2,4,1,true><<<dim3(mt, 1), 512, 0, stream>>>(
      nullptr, x, nullptr, nullptr, Wt1, b_lin1, h, N, 512, 512, 256, nullptr, nullptr, 0);

  // --- graph preprocessing: partition, then fused count/scan/scatter ---
  partA_kernel<<<dim3((E2 + PCH - 1)/PCH, 2), 256, 0, stream>>>(ei1, E1, ei2, E2, bcur, staging, NB);
  degpartB_kernel<<<dim3(NB, 2), 256, 0, stream>>>(staging, bcur, dis1, dis2, goff1, goff2,
                                                   csr1, csr2, NB, N, (unsigned)N,
                                                   cap1r, cap2r, capb1, capb2);

  // --- layer 1: T = fp8(dis_set[r] * (h @ W_c1)[r]), then one conv pass ---
  gemm_kernel<4,4,2,2,4,false><<<dim3(mt, 1), 256, 0, stream>>>(
      h, nullptr, nullptr, nullptr, Wtc1, nullptr, T, N, 256, 256, 0, dis1, dis2, ntab);
  conv_kernel<<<dim3(cb, 2), 256, 0, stream>>>(goff1, csr1, dis1, goff2, csr2, dis2,
                                               T, b_c1, R1, N, ntab);
  // --- layer 2: T = fp8(dis_set[r] * (R1 @ W_c2)[r]), conv ---
  gemm_kernel<4,4,2,2,4,false><<<dim3(mt, 1), 256, 0, stream>>>(
      R1, nullptr, nullptr, nullptr, Wtc2, nullptr, T, N, 256, 256, 0, dis1, dis2, ntab);
  conv_kernel<<<dim3(cb, 2), 256, 0, stream>>>(goff1, csr1, dis1, goff2, csr2, dis2,
                                               T, b_c2, R2, N, ntab);
  // --- head: logits = [h|R1|R2] @ W_lin2 + b, fused log_softmax ---
  gemm_kernel<2,4,4,1,2,false><<<dim3(mt, 1), 256, 0, stream>>>(
      h, nullptr, R1, R2, Wtf, b_lin2, d_out, N, 768, 256, 40, nullptr, nullptr, 0);
}

// Round 16
// 234.240 us; speedup vs baseline: 1.0978x; 1.0978x over previous
//
#include <hip/hip_runtime.h>
#include <hip/hip_bf16.h>
#include <stdint.h>
#include <math.h>

typedef __attribute__((ext_vector_type(8))) short bf16x8;
typedef __attribute__((ext_vector_type(8))) unsigned short ushort8v;
typedef __attribute__((ext_vector_type(4))) float f32x4;
typedef __attribute__((ext_vector_type(2))) float f32x2;
typedef __attribute__((ext_vector_type(4))) unsigned int u32x4;
typedef unsigned long long ull;

__device__ __forceinline__ void load_lds16(const void* g, void* l){
  __builtin_amdgcn_global_load_lds((const __attribute__((address_space(1))) void*)g,
                                   (__attribute__((address_space(3))) void*)l, 16, 0, 0);
}

__device__ __forceinline__ float bf2f(unsigned int u){
  union { unsigned int i; float f; } x; x.i = u << 16; return x.f;
}
__device__ __forceinline__ unsigned short f2bf(float f){
  __hip_bfloat16 h = __float2bfloat16(f);
  unsigned short u;
  __builtin_memcpy(&u, &h, 2);
  return u;
}

// ---------- fused weight transposes + bucket-cursor init (one dispatch) ----------
__global__ void wtrans4_kernel(const float* __restrict__ W1, unsigned short* __restrict__ Wt1,
                               const float* __restrict__ Wc1, unsigned short* __restrict__ Wtc1,
                               const float* __restrict__ Wc2, unsigned short* __restrict__ Wtc2,
                               const float* __restrict__ Wf, unsigned short* __restrict__ Wtf,
                               int NB, int cap1r, int cap2r, int* __restrict__ bcur,
                               unsigned* __restrict__ Tz0, unsigned* __restrict__ Tz1){
  int idx = blockIdx.x*256 + threadIdx.x;
  if (idx >= 245760){                       // binit tail
    int i = idx - 245760;
    if (i < NB) bcur[i] = i*cap1r;
    else if (i < 2*NB) bcur[i] = NB*cap1r + (i - NB)*cap2r;
    else if (i < 2*NB + 32) Tz0[i - 2*NB] = 0u;
    else if (i < 2*NB + 64) Tz1[i - 2*NB - 32] = 0u;
    return;
  }
  const float* W; unsigned short* Wt; int K, N;
  if (idx < 131072){ W = W1; Wt = Wt1; K = 512; N = 256; }
  else if (idx < 163840){ idx -= 131072; W = Wc1; Wt = Wtc1; K = 256; N = 128; }
  else if (idx < 196608){ idx -= 163840; W = Wc2; Wt = Wtc2; K = 256; N = 128; }
  else { idx -= 196608; W = Wf; Wt = Wtf; K = 768; N = 40; }
  int nn = idx / K, kk = idx - nn*K;
  float v = (nn < N) ? W[(size_t)kk*N + nn] : 0.f;
  Wt[idx] = f2bf(v);
}

// ---------- graph preprocessing (bucketed, atomic-light, fixed-capacity) ----------
// Buckets of 128 destination nodes. Staging AND the final CSR are both
// bucket-strided with fixed +17sigma capacities -> NO global scans needed.
// partA partitions edges into staging; degpartB (one kernel) counts,
// LDS-scans padded degrees, writes dis + per-bucket goff[129], scatters
// into csr with LDS cursors, pads nodes to 8-multiples, fills 64 slack
// records. PCH=4096 + 16 edges/thread: R15 showed PCH=2048 (8/thread)
// regresses -- per-thread MLP matters more than block-count tail.
#define PCH 4096

// Pass A: partition PCH-edge chunks into bucket staging
__global__ __launch_bounds__(256) void partA_kernel(
    const int* __restrict__ ei1, int E1, const int* __restrict__ ei2, int E2,
    int* __restrict__ bcur, unsigned* __restrict__ staging, int NB)
{
  const int set = blockIdx.y;
  const int* __restrict__ ei = set ? ei2 : ei1;
  const int E = set ? E2 : E1;
  int* __restrict__ cur = bcur + set*NB;
  __shared__ int hist[400];
  __shared__ int resv[400];
  const int tid = threadIdx.x;
  const int base = blockIdx.x * PCH;
  if (base >= E) return;
  for (int b = tid; b < NB; b += 256) hist[b] = 0;
  __syncthreads();

  if (base + PCH <= E){
    // fast path: 16 edges/thread, rows+cols vector-loaded up front (8x int4 in flight)
    const int t0 = base + tid*16;
    int4 c[4], r[4];
    #pragma unroll
    for (int j = 0; j < 4; ++j) c[j] = *(const int4*)(ei + E + t0 + j*4);
    #pragma unroll
    for (int j = 0; j < 4; ++j) r[j] = *(const int4*)(ei + t0 + j*4);
    #pragma unroll
    for (int j = 0; j < 4; ++j){
      atomicAdd(&hist[c[j].x >> 7], 1); atomicAdd(&hist[c[j].y >> 7], 1);
      atomicAdd(&hist[c[j].z >> 7], 1); atomicAdd(&hist[c[j].w >> 7], 1);
    }
    __syncthreads();
    for (int b = tid; b < NB; b += 256){
      int hc = hist[b];
      resv[b] = hc ? atomicAdd(&cur[b], hc) : 0;
      hist[b] = 0;                      // reuse as local cursor
    }
    __syncthreads();
    #pragma unroll
    for (int j = 0; j < 4; ++j){
      int cc, rr, b, s;
      cc = c[j].x; rr = r[j].x; b = cc >> 7;
      s = resv[b] + atomicAdd(&hist[b], 1);
      staging[s] = ((unsigned)rr << 7) | (unsigned)(cc & 127);
      cc = c[j].y; rr = r[j].y; b = cc >> 7;
      s = resv[b] + atomicAdd(&hist[b], 1);
      staging[s] = ((unsigned)rr << 7) | (unsigned)(cc & 127);
      cc = c[j].z; rr = r[j].z; b = cc >> 7;
      s = resv[b] + atomicAdd(&hist[b], 1);
      staging[s] = ((unsigned)rr << 7) | (unsigned)(cc & 127);
      cc = c[j].w; rr = r[j].w; b = cc >> 7;
      s = resv[b] + atomicAdd(&hist[b], 1);
      staging[s] = ((unsigned)rr << 7) | (unsigned)(cc & 127);
    }
  } else {
    // tail path: guarded scalar
    for (int i = 0; i < PCH/256; ++i){
      int e = base + i*256 + tid;
      if (e < E) atomicAdd(&hist[ei[E + e] >> 7], 1);
    }
    __syncthreads();
    for (int b = tid; b < NB; b += 256){
      int hc = hist[b];
      resv[b] = hc ? atomicAdd(&cur[b], hc) : 0;
      hist[b] = 0;
    }
    __syncthreads();
    for (int i = 0; i < PCH/256; ++i){
      int e = base + i*256 + tid;
      if (e < E){
        int c = ei[E + e], r = ei[e];
        int b = c >> 7;
        int s = resv[b] + atomicAdd(&hist[b], 1);
        staging[s] = ((unsigned)r << 7) | (unsigned)(c & 127);
      }
    }
  }
}

// Fused: count + LDS scan + dis/goff write + local scatter + pad + slack fill.
// goff layout: [b*129 + local] = absolute record offset of node start;
// slot 128 = bucket end-of-used. csr is bucket-strided (capb records/bucket).
__global__ __launch_bounds__(256) void degpartB_kernel(
    const unsigned* __restrict__ staging, const int* __restrict__ bcur,
    float* __restrict__ dis1, float* __restrict__ dis2,
    int* __restrict__ goff1, int* __restrict__ goff2,
    unsigned* __restrict__ csr1, unsigned* __restrict__ csr2,
    int NB, int n, unsigned padrow, int cap1r, int cap2r, int capb1, int capb2)
{
  const int set = blockIdx.y;
  float* __restrict__ dis = set ? dis2 : dis1;
  int* __restrict__ goff = set ? goff2 : goff1;
  unsigned* __restrict__ csr = set ? csr2 : csr1;
  const int capb = set ? capb2 : capb1;
  const int b = blockIdx.x;
  const int nodebase = b << 7;
  const int nn = min(128, n - nodebase);
  if (nn <= 0) return;
  __shared__ int cnt[128];
  __shared__ int offv[129];
  __shared__ int curl[128];
  const int tid = threadIdx.x;
  if (tid < 128) cnt[tid] = 0;
  __syncthreads();
  const int s0 = set ? (NB*cap1r + b*cap2r) : (b*cap1r);
  const int s1 = bcur[set*NB + b];
  for (int i = s0 + tid; i < s1; i += 256)
    atomicAdd(&cnt[staging[i] & 127], 1);
  __syncthreads();
  // Hillis-Steele inclusive scan of padded counts (128 entries, in curl)
  int pc = 0;
  if (tid < 128){ pc = (cnt[tid] + 7) & ~7; curl[tid] = pc; }
  __syncthreads();
  for (int o = 1; o < 128; o <<= 1){
    int t = 0;
    if (tid < 128 && tid >= o) t = curl[tid - o];
    __syncthreads();
    if (tid < 128) curl[tid] += t;
    __syncthreads();
  }
  const int cbase = b * capb;
  if (tid < 128){
    offv[tid] = cbase + curl[tid] - pc;       // exclusive start
    if (tid == 127) offv[128] = cbase + curl[127];
  }
  __syncthreads();
  if (tid <= 128) goff[b*129 + tid] = offv[tid];
  if (tid < nn){
    int c = cnt[tid];
    dis[nodebase + tid] = (c > 0) ? (1.0f/sqrtf((float)c)) : 0.f;
  }
  if (tid < 128) curl[tid] = 0;
  __syncthreads();
  // local scatter with LDS cursors (no global atomics)
  for (int i = s0 + tid; i < s1; i += 256){
    unsigned v = staging[i];
    int cl = v & 127;
    int p = offv[cl] + atomicAdd(&curl[cl], 1);
    csr[p] = v >> 7;
  }
  __syncthreads();
  // pad each node to its 8-multiple region; fill 64 slack records past end
  for (int c = tid; c < 128; c += 256){
    int p1 = offv[c + 1];
    for (int p = offv[c] + cnt[c]; p < p1; ++p) csr[p] = padrow;
  }
  if (tid < 64) csr[offv[128] + tid] = padrow;
}

// ---------- GCN aggregation: out[c] = dis[c] * sum_e T_set[r] + b ----------
// T rows PRE-SCALED by dis_set[r], fp8 e4m3 (128B/row = 2 lines/edge).
// KN=8 consecutive nodes per wave (R15: KN=16 regressed -- queue depth /
// wave backfill beats single-round residency on this latency-bound loop).
// One 2-stage pipeline streams the contiguous padded-CSR range; node
// boundaries via shfl-indexed register cache (wave-uniform). KN | 128 so
// a wave never crosses a bucket.
#define KN 8
__global__ __launch_bounds__(256) void conv_kernel(
    const int* __restrict__ goff1, const unsigned* __restrict__ csr1, const float* __restrict__ dis1,
    const int* __restrict__ goff2, const unsigned* __restrict__ csr2, const float* __restrict__ dis2,
    const unsigned char* __restrict__ Tbase,   // [2][ntab][128] fp8
    const float* __restrict__ bias, unsigned short* __restrict__ outR,
    int n, int ntab)
{
  const int set = blockIdx.y;
  const int* __restrict__ goff = set ? goff2 : goff1;
  const float* __restrict__ dis = set ? dis2 : dis1;
  const unsigned* __restrict__ csrq = set ? csr2 : csr1;
  const int col_ofs = set ? 128 : 0;
  const unsigned* __restrict__ tab =
      (const unsigned*)(Tbase + (size_t)set * ntab * 128);

  const int wv0 = (blockIdx.x*4 + (threadIdx.x >> 6)) * KN;
  if (wv0 >= n) return;
  const int wend = min(n, wv0 + KN);
  const int l = threadIdx.x & 63;
  const int half = l >> 5, lf = l & 31;
  const float b0 = bias[lf*4 + 0], b1 = bias[lf*4 + 1];
  const float b2 = bias[lf*4 + 2], b3 = bias[lf*4 + 3];

  // lanes 0..KN hold goff[node .. bucket-local]; shfl-indexed boundary cache
  const int gbase = (wv0 >> 7)*129 + (wv0 & 127);
  const int offs = goff[gbase + min(l, wend - wv0)];
  const int cstart = __shfl(offs, 0, 64);
  const int pend   = __shfl(offs, wend - wv0, 64);
  int node = wv0;
  int nxt  = __shfl(offs, min(1, wend - wv0), 64);

  float ax = 0.f, ay = 0.f, az = 0.f, aw = 0.f;

#define EMIT_NODE { \
    float rx = ax + __shfl_xor(ax, 32, 64); \
    float ry = ay + __shfl_xor(ay, 32, 64); \
    float rz = az + __shfl_xor(az, 32, 64); \
    float rw = aw + __shfl_xor(aw, 32, 64); \
    if (half == 0){ \
      const float dc = dis[node]; \
      ull ov = (ull)((unsigned)f2bf(fmaf(dc, rx, b0)) | ((unsigned)f2bf(fmaf(dc, ry, b1)) << 16)) \
             | ((ull)((unsigned)f2bf(fmaf(dc, rz, b2)) | ((unsigned)f2bf(fmaf(dc, rw, b3)) << 16)) << 32); \
      __builtin_nontemporal_store(ov, (ull*)&outR[(size_t)node*256 + col_ofs + lf*4]); \
    } \
    ax = ay = az = aw = 0.f; }
#define DRAIN(CUR) \
    while (node < wend && (CUR) == nxt){ \
      EMIT_NODE \
      ++node; \
      nxt = __shfl(offs, min(node + 1 - wv0, KN), 64); \
    }

  DRAIN(cstart)                              // leading empty nodes

  const int nbat = (pend - cstart) >> 3;     // 8-edge batches, exact (padded)
  if (nbat > 0){
    const unsigned* cp = csrq + cstart + half*4;
    u32x4 qa, qb;
    unsigned va0, va1, va2, va3, vb0, vb1, vb2, vb3;

#define LQ(q, B) q = __builtin_nontemporal_load((const u32x4*)(cp + (B)*8));
#define GATH(v, q) \
    v##0 = tab[(size_t)q.x * 32 + lf]; \
    v##1 = tab[(size_t)q.y * 32 + lf]; \
    v##2 = tab[(size_t)q.z * 32 + lf]; \
    v##3 = tab[(size_t)q.w * 32 + lf];
#define FMA1(v) { \
    f32x2 lo = __builtin_amdgcn_cvt_pk_f32_fp8((int)v, false); \
    f32x2 hi = __builtin_amdgcn_cvt_pk_f32_fp8((int)v, true);  \
    ax += lo.x; ay += lo.y; az += hi.x; aw += hi.y; }
#define FMAB(v) { FMA1(v##0) FMA1(v##1) FMA1(v##2) FMA1(v##3) }

    LQ(qa, 0)
    GATH(va, qa)
    LQ(qb, 1)
    int b = 0;
    while (b + 2 <= nbat){
      LQ(qa, b + 2)              // speculative reads stay inside filled bucket (64-slack)
      GATH(vb, qb)
      FMAB(va)
      DRAIN(cstart + (b + 1)*8)
      LQ(qb, b + 3)
      GATH(va, qa)               // pad/slack rows hit the zeroed T row; harmless
      FMAB(vb)
      DRAIN(cstart + (b + 2)*8)
      b += 2;
    }
    if (b < nbat){
      FMAB(va)
      DRAIN(cstart + nbat*8)
    }
#undef LQ
#undef GATH
#undef FMA1
#undef FMAB
  }
  while (node < wend){ EMIT_NODE ++node; }
#undef EMIT_NODE
#undef DRAIN
}

// ---------- bf16 MFMA GEMM, m97-style 2-barrier loop ----------
// Thread count = WGM*WGN*64 (256 for most instances; 512 for BN=256 GEMM1).
// A [M x K] bf16 row-major (lda); AF32: A is f32, converted to bf16 during
// reg-staging (fuses the cvt pass; BN=256 single-pass reads x ONCE).
// Bt = B^T stored [BN_total x K] bf16.
// EPI 1: +bias, relu, bf16 store;
// EPI 2: A = 3 slabs (h|R1|R2, lda=256 each), +bias, fused log_softmax, f32 store;
// EPI 4: dual fp8 table store T[set][row][col] = fp8(vv * dis_set[row]).
template<int FM, int FN, int WGM, int WGN, int EPI, bool AF32>
__global__ __launch_bounds__(WGM*WGN*64, (WGM*WGN*64) == 512 ? 4 : 2) void gemm_kernel(
    const unsigned short* __restrict__ A0, const float* __restrict__ Af,
    const unsigned short* __restrict__ A1, const unsigned short* __restrict__ A2,
    const unsigned short* __restrict__ Bt, const float* __restrict__ bias,
    void* __restrict__ Cout, int M, int K, int lda, int ldc,
    const float* __restrict__ d1, const float* __restrict__ d2, int ntab)
{
  constexpr int THREADS = WGM*WGN*64;
  constexpr int BM = WGM*FM*16;
  constexpr int BN = WGN*FN*16;
  constexpr int BK = 32;
  constexpr int AJ = (BM*BK/8)/THREADS;   // 16B chunks per thread for A
  constexpr int BJ = (BN*BK/8)/THREADS;   // 16B chunks per thread for B
  static_assert(BM == 128, "staging assumes BM==128");
  __shared__ unsigned short As[BM][BK];
  __shared__ unsigned short Bs[BN][BK];
  const int tid = threadIdx.x;
  const int w = tid >> 6, l = tid & 63;
  const int wr = w / WGN, wc = w % WGN;
  const int m0 = blockIdx.x*BM, n0 = blockIdx.y*BN;
  f32x4 acc[FM][FN] = {};
  const int nsteps = K / BK;
  for (int s = 0; s < nsteps; ++s){
    const int k0 = s*BK;
    const unsigned short* Asrc = A0;
    int kin = k0;
    if constexpr (EPI == 2){
      int slab = k0 >> 8;
      Asrc = (slab == 0) ? A0 : ((slab == 1) ? A1 : A2);
      kin = k0 & 255;
    }
    __syncthreads();
    if constexpr (AF32){
      #pragma unroll
      for (int j = 0; j < AJ; ++j){        // A: load f32, cvt, store 16B to LDS
        int idx = j*THREADS + tid;
        int row = idx >> 2, kq = idx & 3;
        int rg = m0 + row; rg = (rg < M) ? rg : (M - 1);
        const float* src = Af + (size_t)rg*lda + kin + kq*8;
        float4 a = *(const float4*)src;
        float4 b2 = *(const float4*)(src + 4);
        ushort8v u;
        u[0] = f2bf(a.x);  u[1] = f2bf(a.y);  u[2] = f2bf(a.z);  u[3] = f2bf(a.w);
        u[4] = f2bf(b2.x); u[5] = f2bf(b2.y); u[6] = f2bf(b2.z); u[7] = f2bf(b2.w);
        *(ushort8v*)((char*)&As[0][0] + (size_t)idx*16) = u;
      }
    } else {
      #pragma unroll
      for (int j = 0; j < AJ; ++j){        // A: async 16B global->LDS
        int idx = j*THREADS + tid;
        int row = idx >> 2, kq = idx & 3;
        int rg = m0 + row; rg = (rg < M) ? rg : (M - 1);
        load_lds16(Asrc + (size_t)rg*lda + kin + kq*8,
                   ((char*)&As[0][0]) + (size_t)(j*THREADS + w*64)*16);
      }
    }
    #pragma unroll
    for (int j = 0; j < BJ; ++j){          // Bt: [n][k] layout, same pattern as A
      int idx = j*THREADS + tid;
      int row = idx >> 2, kq = idx & 3;
      load_lds16(Bt + (size_t)(n0 + row)*K + k0 + kq*8,
                 ((char*)&Bs[0][0]) + (size_t)(j*THREADS + w*64)*16);
    }
    __syncthreads();
    bf16x8 af[FM], bfr[FN];
    const int kofs = (l >> 4)*8, l16 = l & 15;
    #pragma unroll
    for (int mi = 0; mi < FM; ++mi)
      af[mi] = *(const bf16x8*)&As[wr*FM*16 + mi*16 + l16][kofs];
    #pragma unroll
    for (int ni = 0; ni < FN; ++ni)
      bfr[ni] = *(const bf16x8*)&Bs[wc*FN*16 + ni*16 + l16][kofs];
    #pragma unroll
    for (int mi = 0; mi < FM; ++mi)
      #pragma unroll
      for (int ni = 0; ni < FN; ++ni)
        acc[mi][ni] = __builtin_amdgcn_mfma_f32_16x16x32_bf16(af[mi], bfr[ni], acc[mi][ni], 0, 0, 0);
  }
  const int lg = l >> 4, lc = l & 15;
  if constexpr (EPI == 2){
    float* O = (float*)Cout;
    #pragma unroll
    for (int mi = 0; mi < FM; ++mi){
      #pragma unroll
      for (int i = 0; i < 4; ++i){
        int row = m0 + wr*FM*16 + mi*16 + lg*4 + i;
        float v[FN];
        float mx = -1e30f;
        #pragma unroll
        for (int ni = 0; ni < FN; ++ni){
          int col = ni*16 + lc;                       // WGN==1, n0==0
          v[ni] = acc[mi][ni][i] + ((col < 40) ? bias[col] : 0.f);
          if (col < 40) mx = fmaxf(mx, v[ni]);
        }
        #pragma unroll
        for (int d = 1; d < 16; d <<= 1) mx = fmaxf(mx, __shfl_xor(mx, d, 64));
        float se = 0.f;
        #pragma unroll
        for (int ni = 0; ni < FN; ++ni){
          int col = ni*16 + lc;
          if (col < 40) se += expf(v[ni] - mx);
        }
        #pragma unroll
        for (int d = 1; d < 16; d <<= 1) se += __shfl_xor(se, d, 64);
        float lse = logf(se);
        if (row < M){
          #pragma unroll
          for (int ni = 0; ni < FN; ++ni){
            int col = ni*16 + lc;
            if (col < 40) O[(size_t)row*40 + col] = v[ni] - mx - lse;
          }
        }
      }
    }
  } else if constexpr (EPI == 4){
    unsigned char* T = (unsigned char*)Cout;            // [2][ntab][128]
    #pragma unroll
    for (int mi = 0; mi < FM; ++mi){
      #pragma unroll
      for (int i = 0; i < 4; ++i){
        int row = m0 + wr*FM*16 + mi*16 + lg*4 + i;
        if (row >= M) continue;
        float s1 = d1[row], s2 = d2[row];
        #pragma unroll
        for (int ni = 0; ni < FN; ++ni){
          int col = n0 + wc*FN*16 + ni*16 + lc;        // [0,128)
          float vv = acc[mi][ni][i];
          unsigned p1 = (unsigned)__builtin_amdgcn_cvt_pk_fp8_f32(vv*s1, vv*s1, 0, false);
          unsigned p2 = (unsigned)__builtin_amdgcn_cvt_pk_fp8_f32(vv*s2, vv*s2, 0, false);
          T[(size_t)row*128 + col] = (unsigned char)(p1 & 0xff);
          T[((size_t)ntab + row)*128 + col] = (unsigned char)(p2 & 0xff);
        }
      }
    }
  } else {
    unsigned short* C = (unsigned short*)Cout;
    #pragma unroll
    for (int mi = 0; mi < FM; ++mi){
      #pragma unroll
      for (int i = 0; i < 4; ++i){
        int row = m0 + wr*FM*16 + mi*16 + lg*4 + i;
        if (row >= M) continue;
        #pragma unroll
        for (int ni = 0; ni < FN; ++ni){
          int col = n0 + wc*FN*16 + ni*16 + lc;
          float vv = acc[mi][ni][i];
          if constexpr (EPI == 1){ vv += bias[col]; vv = fmaxf(vv, 0.f); }
          C[(size_t)row*ldc + col] = f2bf(vv);
        }
      }
    }
  }
}

extern "C" void kernel_launch(void* const* d_in, const int* in_sizes, int n_in,
                              void* d_out, int out_size, void* d_ws, size_t ws_size,
                              hipStream_t stream)
{
  (void)n_in; (void)out_size;
  const float* x      = (const float*)d_in[0];
  const int*   ei1    = (const int*)d_in[1];
  const int*   ei2    = (const int*)d_in[2];
  const float* W_lin1 = (const float*)d_in[3];
  const float* b_lin1 = (const float*)d_in[4];
  const float* W_c1   = (const float*)d_in[5];
  const float* b_c1   = (const float*)d_in[6];
  const float* W_c2   = (const float*)d_in[7];
  const float* b_c2   = (const float*)d_in[8];
  const float* W_lin2 = (const float*)d_in[9];
  const float* b_lin2 = (const float*)d_in[10];

  const int N  = in_sizes[0] / 512;
  const int E1 = in_sizes[1] / 2;
  const int E2 = in_sizes[2] / 2;
  const int ntab = N + 1;                    // +1 zero row for pad edges
  const int NB = (N + 127) >> 7;             // destination buckets of 128 nodes
  // fixed per-bucket staging capacities (uniform edges: mean + >17 sigma)
  const int cap1r = (((E1 + NB - 1)/NB + 768) + 63) & ~63;
  const int cap2r = (((E2 + NB - 1)/NB + 1536) + 63) & ~63;
  // fixed per-bucket CSR capacities: mean + 17 sigma + max pad (7*128) + 64 slack
  const int mb1 = (int)(128.0*E1/N), mb2 = (int)(128.0*E2/N);
  const int capb1 = (mb1 + (int)(17.0*sqrt((double)mb1)) + 896 + 64 + 63) & ~63;
  const int capb2 = (mb2 + (int)(17.0*sqrt((double)mb2)) + 896 + 64 + 63) & ~63;

  char* base = (char*)d_ws;
  size_t off = 0;
  auto alloc = [&](size_t bytes) -> char* {
    off = (off + 255) & ~(size_t)255;
    char* r = base + off;
    off += bytes;
    return r;
  };

  unsigned short* h    = (unsigned short*)alloc((size_t)N*256*2);
  unsigned char*  T    = (unsigned char*)alloc((size_t)2*ntab*128); // fp8 scaled tables
  unsigned short* R1   = (unsigned short*)alloc((size_t)N*256*2);
  unsigned short* R2   = (unsigned short*)alloc((size_t)N*256*2);
  unsigned short* Wt1  = (unsigned short*)alloc((size_t)256*512*2);
  unsigned short* Wtc1 = (unsigned short*)alloc((size_t)128*256*2);
  unsigned short* Wtc2 = (unsigned short*)alloc((size_t)128*256*2);
  unsigned short* Wtf  = (unsigned short*)alloc((size_t)64*768*2); // W_lin2^T padded to 64 cols
  float* dis1 = (float*)alloc((size_t)N*4);
  float* dis2 = (float*)alloc((size_t)N*4);
  int* goff1 = (int*)alloc((size_t)NB*129*4);
  int* goff2 = (int*)alloc((size_t)NB*129*4);
  int* bcur  = (int*)alloc((size_t)2*NB*4);
  unsigned* csr1 = (unsigned*)alloc((size_t)NB*capb1*4);
  unsigned* csr2 = (unsigned*)alloc((size_t)NB*capb2*4);
  unsigned* staging = (unsigned*)alloc((size_t)NB*((size_t)cap1r + cap2r)*4);
  if (off > ws_size) return;   // workspace insufficient -> visible validation failure

  int mt = (N + 127)/128;
  int nwv = (N + KN - 1)/KN;
  int cb = (nwv + 3)/4;

  // --- fused weight transposes + bucket-cursor init ---
  wtrans4_kernel<<<(245760 + 2*NB + 64 + 255)/256, 256, 0, stream>>>(
      W_lin1, Wt1, W_c1, Wtc1, W_c2, Wtc2, W_lin2, Wtf,
      NB, cap1r, cap2r, bcur,
      (unsigned*)(T + (size_t)N*128), (unsigned*)(T + ((size_t)ntab + N)*128));
  // h = relu(x @ W_lin1 + b): BN=256 single pass, x f32 read ONCE (fused cvt)
  gemm_kernel<4,4,2,4,1,true><<<dim3(mt, 1), 512, 0, stream>>>(
      nullptr, x, nullptr, nullptr, Wt1, b_lin1, h, N, 512, 512, 256, nullptr, nullptr, 0);

  // --- graph preprocessing: partition, then fused count/scan/scatter ---
  partA_kernel<<<dim3((E2 + PCH - 1)/PCH, 2), 256, 0, stream>>>(ei1, E1, ei2, E2, bcur, staging, NB);
  degpartB_kernel<<<dim3(NB, 2), 256, 0, stream>>>(staging, bcur, dis1, dis2, goff1, goff2,
                                                   csr1, csr2, NB, N, (unsigned)N,
                                                   cap1r, cap2r, capb1, capb2);

  // --- layer 1: T = fp8(dis_set[r] * (h @ W_c1)[r]), then one conv pass ---
  gemm_kernel<4,4,2,2,4,false><<<dim3(mt, 1), 256, 0, stream>>>(
      h, nullptr, nullptr, nullptr, Wtc1, nullptr, T, N, 256, 256, 0, dis1, dis2, ntab);
  conv_kernel<<<dim3(cb, 2), 256, 0, stream>>>(goff1, csr1, dis1, goff2, csr2, dis2,
                                               T, b_c1, R1, N, ntab);
  // --- layer 2: T = fp8(dis_set[r] * (R1 @ W_c2)[r]), conv ---
  gemm_kernel<4,4,2,2,4,false><<<dim3(mt, 1), 256, 0, stream>>>(
      R1, nullptr, nullptr, nullptr, Wtc2, nullptr, T, N, 256, 256, 0, dis1, dis2, ntab);
  conv_kernel<<<dim3(cb, 2), 256, 0, stream>>>(goff1, csr1, dis1, goff2, csr2, dis2,
                                               T, b_c2, R2, N, ntab);
  // --- head: logits = [h|R1|R2] @ W_lin2 + b, fused log_softmax ---
  gemm_kernel<2,4,4,1,2,false><<<dim3(mt, 1), 256, 0, stream>>>(
      h, nullptr, R1, R2, Wtf, b_lin2, d_out, N, 768, 256, 40, nullptr, nullptr, 0);
}